// Round 9
// baseline (6080.896 us; speedup 1.0000x reference)
//
#include <hip/hip_runtime.h>

#define XESTR 68   // xeL row stride (floats)

__device__ __forceinline__ unsigned long long pack_key(float s, int col) {
    unsigned u = __float_as_uint(s);
    unsigned m = (u & 0x80000000u) ? ~u : (u | 0x80000000u);
    return ((unsigned long long)m << 32) | (unsigned)(127 - col);
}
__device__ __forceinline__ float key_val(unsigned long long k) {
    unsigned m = (unsigned)(k >> 32);
    unsigned u = (m & 0x80000000u) ? (m ^ 0x80000000u) : ~m;
    return __uint_as_float(u);
}
__device__ __forceinline__ int key_col(unsigned long long k) {
    return 127 - (int)(k & 0xFFFFFFFFu);
}
__device__ __forceinline__ void ins3(unsigned long long x,
        unsigned long long &a0, unsigned long long &a1, unsigned long long &a2) {
    if (x > a0)      { a2 = a1; a1 = a0; a0 = x; }
    else if (x > a1) { a2 = a1; a1 = x; }
    else if (x > a2) { a2 = x; }
}

// codebook row norms, f64 accumulation — verbatim (validated)
__global__ void rn_kernel(const float* __restrict__ cb, float* __restrict__ rn) {
    const int j = blockIdx.x;
    const int t = threadIdx.x;
    double a = 0.0;
#pragma unroll
    for (int m = 0; m < 8; ++m) {
        float f = cb[j * 512 + m * 64 + t];
        a += (double)f * (double)f;
    }
#pragma unroll
    for (int off = 32; off >= 1; off >>= 1)
        a += __shfl_down(a, off);
    if (t == 0) rn[j] = (float)sqrt(a);
}

__global__ __launch_bounds__(256, 2) void fused_kernel(
    const float* __restrict__ x, const float* __restrict__ cb,
    const float* __restrict__ W, const float* __restrict__ bias,
    const float* __restrict__ u, const float* __restrict__ v,
    const float* __restrict__ rn, float* __restrict__ out,
    size_t idx_off, size_t val_off)
{
    __shared__ __align__(16) float xeL[64 * XESTR];       // xe chunk [64][64]
    __shared__ unsigned long long candL[64 * 12];          // per-row per-wave top3
    __shared__ float rnL[128];
    __shared__ float xnL[64];
    __shared__ unsigned char idxL[64 * 3];

    const int tid = threadIdx.x;
    const int tlo = tid & 15;
    const int thi = tid >> 4;          // 0..15 block-wide
    const int w   = tid >> 6;          // wave 0..3
    const int lane = tid & 63;
    const int row0 = blockIdx.x << 6;

    if (tid < 128) rnL[tid] = rn[tid];

    // global operand bases (read direct; same bits as staged copies)
    const float* xr0 = x + (size_t)(row0 + thi) * 512;          // rows thi+16i via +16*512*i
    float m2[4][8];                      // sims acc: rows tlo+16i, cols thi+16j
#pragma unroll
    for (int i = 0; i < 4; ++i)
#pragma unroll
        for (int j = 0; j < 8; ++j) m2[i][j] = 0.f;
    float nacc = 0.f;                    // |xe_row|^2 for tid<64 (exact R4 chain)

    for (int dc = 0; dc < 8; ++dc) {
        float m1[4][4];                  // xe acc: rows thi+16i, cols tlo+16j
#pragma unroll
        for (int i = 0; i < 4; ++i)
#pragma unroll
            for (int j = 0; j < 4; ++j) m1[i][j] = 0.f;

        const float* wr0 = W + (size_t)(dc * 64 + tlo) * 512;   // rows tlo+16j via +16*512*j

        for (int kc = 0; kc < 8; ++kc) {
            float s1[4][4];              // per-64-chunk sub-accumulator (bit-exact scheme)
#pragma unroll
            for (int i = 0; i < 4; ++i)
#pragma unroll
                for (int j = 0; j < 4; ++j) s1[i][j] = 0.f;
            const int ko = kc * 64;
#pragma unroll
            for (int kk = 0; kk < 16; ++kk) {
                float4 wa[4];
#pragma unroll
                for (int j = 0; j < 4; ++j)
                    wa[j] = *(const float4*)(wr0 + (size_t)(16 * j) * 512 + ko + (kk << 2));
#pragma unroll
                for (int i = 0; i < 4; ++i) {
                    const float4 xa = *(const float4*)(xr0 + (size_t)(16 * i) * 512 + ko + (kk << 2));
#pragma unroll
                    for (int j = 0; j < 4; ++j) {
                        s1[i][j] = fmaf(xa.x, wa[j].x, s1[i][j]);
                        s1[i][j] = fmaf(xa.y, wa[j].y, s1[i][j]);
                        s1[i][j] = fmaf(xa.z, wa[j].z, s1[i][j]);
                        s1[i][j] = fmaf(xa.w, wa[j].w, s1[i][j]);
                    }
                }
            }
#pragma unroll
            for (int i = 0; i < 4; ++i)
#pragma unroll
                for (int j = 0; j < 4; ++j) m1[i][j] += s1[i][j];
        }
        __syncthreads();                 // prev dc's xeL readers (norm/P2) done
        // bias + store xe chunk to LDS (verbatim bits)
#pragma unroll
        for (int j = 0; j < 4; ++j) {
            float bj = bias[dc * 64 + tlo + 16 * j];
#pragma unroll
            for (int i = 0; i < 4; ++i)
                xeL[(thi + 16 * i) * XESTR + tlo + 16 * j] = m1[i][j] + bj;
        }
        __syncthreads();                 // xeL visible
        // norm chain (tid<64, d-ascending, exact validated order)
        if (tid < 64) {
#pragma unroll
            for (int dd = 0; dd < 16; ++dd) {
                float4 q = *(const float4*)&xeL[tid * XESTR + (dd << 2)];
                nacc = fmaf(q.x, q.x, nacc);
                nacc = fmaf(q.y, q.y, nacc);
                nacc = fmaf(q.z, q.z, nacc);
                nacc = fmaf(q.w, q.w, nacc);
            }
        }
        // P2: sims partial over this d-chunk; cb read direct from global
        {
            const float* cr0 = cb + (size_t)thi * 512 + dc * 64;   // rows thi+16j
            float s2[4][8];
#pragma unroll
            for (int i = 0; i < 4; ++i)
#pragma unroll
                for (int j = 0; j < 8; ++j) s2[i][j] = 0.f;
#pragma unroll
            for (int dd = 0; dd < 16; ++dd) {
                float4 rv[8];
#pragma unroll
                for (int j = 0; j < 8; ++j)
                    rv[j] = *(const float4*)(cr0 + (size_t)(16 * j) * 512 + (dd << 2));
#pragma unroll
                for (int i = 0; i < 4; ++i) {
                    const float4 xv = *(const float4*)&xeL[(tlo + 16 * i) * XESTR + (dd << 2)];
#pragma unroll
                    for (int j = 0; j < 8; ++j) {
                        s2[i][j] = fmaf(xv.x, rv[j].x, s2[i][j]);
                        s2[i][j] = fmaf(xv.y, rv[j].y, s2[i][j]);
                        s2[i][j] = fmaf(xv.z, rv[j].z, s2[i][j]);
                        s2[i][j] = fmaf(xv.w, rv[j].w, s2[i][j]);
                    }
                }
            }
#pragma unroll
            for (int i = 0; i < 4; ++i)
#pragma unroll
                for (int j = 0; j < 8; ++j) m2[i][j] += s2[i][j];
        }
    }
    if (tid < 64) xnL[tid] = sqrtf(nacc);
    __syncthreads();

    // per-wave top-3 (packed keys, exact tie semantics), then cross-wave merge
#pragma unroll
    for (int i = 0; i < 4; ++i) {
        const int r = tlo + 16 * i;
        const float xn = xnL[r];
        unsigned long long a0 = 0, a1 = 0, a2 = 0;
#pragma unroll
        for (int j = 0; j < 8; ++j) {
            const int c = thi + 16 * j;
            float s = m2[i][j] / fmaxf(xn * rnL[c], 1e-8f);
            ins3(pack_key(s, c), a0, a1, a2);
        }
#pragma unroll
        for (int mask = 16; mask <= 32; mask <<= 1) {
            unsigned long long b0 = __shfl_xor(a0, mask);
            unsigned long long b1 = __shfl_xor(a1, mask);
            unsigned long long b2 = __shfl_xor(a2, mask);
            ins3(b0, a0, a1, a2); ins3(b1, a0, a1, a2); ins3(b2, a0, a1, a2);
        }
        if (lane < 16) {
            candL[r * 12 + w * 3 + 0] = a0;
            candL[r * 12 + w * 3 + 1] = a1;
            candL[r * 12 + w * 3 + 2] = a2;
        }
    }
    __syncthreads();

    if (tid < 64) {
        unsigned long long a0 = 0, a1 = 0, a2 = 0;
#pragma unroll
        for (int m = 0; m < 12; ++m) ins3(candL[tid * 12 + m], a0, a1, a2);
        const size_t g = (size_t)(row0 + tid);
        float* oi = out + idx_off + g * 3;
        float* ov = out + val_off + g * 3;
        oi[0] = (float)key_col(a0); oi[1] = (float)key_col(a1); oi[2] = (float)key_col(a2);
        ov[0] = key_val(a0); ov[1] = key_val(a1); ov[2] = key_val(a2);
        idxL[tid * 3 + 0] = (unsigned char)key_col(a0);
        idxL[tid * 3 + 1] = (unsigned char)key_col(a1);
        idxL[tid * 3 + 2] = (unsigned char)key_col(a2);
    }
    __syncthreads();

    // adapted_centers = cb[idx] + u[tt]*v   (768 tasks over 256 threads, verbatim)
    const float uu0 = u[0], uu1 = u[1], uu2 = u[2];
#pragma unroll
    for (int q = 0; q < 3; ++q) {
        int task = tid + 256 * q;            // 64 rows * 3 tt * 4 seg
        int row = task / 12;
        int rem = task - row * 12;
        int tt  = rem >> 2;
        int seg = rem & 3;
        int idx = idxL[row * 3 + tt];
        float uu = (tt == 0) ? uu0 : ((tt == 1) ? uu1 : uu2);
        const float4* gr4 = (const float4*)(cb + (size_t)idx * 512 + seg * 128);
        const float4* gv4 = (const float4*)(v + seg * 128);
        float4* ob = (float4*)(out + ((size_t)(row0 + row) * 3 + tt) * 512 + seg * 128);
#pragma unroll
        for (int c2 = 0; c2 < 32; ++c2) {
            float4 rv = gr4[c2];
            float4 vv = gv4[c2];
            float4 o;
            o.x = fmaf(uu, vv.x, rv.x);
            o.y = fmaf(uu, vv.y, rv.y);
            o.z = fmaf(uu, vv.z, rv.z);
            o.w = fmaf(uu, vv.w, rv.w);
            ob[c2] = o;
        }
    }
}

extern "C" void kernel_launch(void* const* d_in, const int* in_sizes, int n_in,
                              void* d_out, int out_size, void* d_ws, size_t ws_size,
                              hipStream_t stream) {
    const float* x  = (const float*)d_in[0];
    const float* cb = (const float*)d_in[1];
    const float* W  = (const float*)d_in[2];
    const float* b  = (const float*)d_in[3];
    const float* u  = (const float*)d_in[4];
    const float* v  = (const float*)d_in[5];
    float* rn  = (float*)d_ws;                       // 128 floats scratch
    float* out = (float*)d_out;

    const size_t B = (size_t)in_sizes[0] / 512;      // 131072
    const size_t val_off = (size_t)out_size - 3 * B; // top_k_values
    const size_t idx_off = (size_t)out_size - 6 * B; // top_k_indices

    hipLaunchKernelGGL(rn_kernel, dim3(128), dim3(64), 0, stream, cb, rn);
    hipLaunchKernelGGL(fused_kernel, dim3((unsigned)(B / 64)), dim3(256), 0, stream,
                       x, cb, W, b, u, v, rn, out, idx_off, val_off);
}

// Round 10
// 2305.684 us; speedup vs baseline: 2.6374x; 2.6374x over previous
//
#include <hip/hip_runtime.h>

#define TSTR 68          // uA tile row stride in floats (16B aligned)
#define XESTR 68         // xeL row stride
#define SSTR 129         // sims LDS row stride

__device__ __forceinline__ unsigned long long pack_key(float s, int col) {
    unsigned u = __float_as_uint(s);
    unsigned m = (u & 0x80000000u) ? ~u : (u | 0x80000000u);
    return ((unsigned long long)m << 32) | (unsigned)(127 - col);
}
__device__ __forceinline__ float key_val(unsigned long long k) {
    unsigned m = (unsigned)(k >> 32);
    unsigned u = (m & 0x80000000u) ? (m ^ 0x80000000u) : ~m;
    return __uint_as_float(u);
}
__device__ __forceinline__ int key_col(unsigned long long k) {
    return 127 - (int)(k & 0xFFFFFFFFu);
}
__device__ __forceinline__ void ins3(unsigned long long x,
        unsigned long long &a0, unsigned long long &a1, unsigned long long &a2) {
    if (x > a0)      { a2 = a1; a1 = a0; a0 = x; }
    else if (x > a1) { a2 = a1; a1 = x; }
    else if (x > a2) { a2 = x; }
}

// codebook row norms, f64 accumulation — verbatim (validated)
__global__ void rn_kernel(const float* __restrict__ cb, float* __restrict__ rn) {
    const int j = blockIdx.x;
    const int t = threadIdx.x;
    double a = 0.0;
#pragma unroll
    for (int m = 0; m < 8; ++m) {
        float f = cb[j * 512 + m * 64 + t];
        a += (double)f * (double)f;
    }
#pragma unroll
    for (int off = 32; off >= 1; off >>= 1)
        a += __shfl_down(a, off);
    if (t == 0) rn[j] = (float)sqrt(a);
}

__global__ __launch_bounds__(256, 2) void fused_kernel(
    const float* __restrict__ x, const float* __restrict__ cb,
    const float* __restrict__ W, const float* __restrict__ bias,
    const float* __restrict__ u, const float* __restrict__ v,
    const float* __restrict__ rn, float* __restrict__ out,
    size_t idx_off, size_t val_off)
{
    __shared__ __align__(16) float uA[128 * TSTR];   // x+W tiles | cb tile | sims dump
    __shared__ __align__(16) float xeL[64 * XESTR];  // xe chunk [64][64]
    __shared__ float rnL[128];
    __shared__ float xnL[64];
    __shared__ unsigned char idxL[64 * 3];

    const int tid = threadIdx.x;
    const int tlo = tid & 15;
    const int thi = tid >> 4;
    const int row0 = blockIdx.x << 6;

    if (tid < 128) rnL[tid] = rn[tid];

    const int srow = tid >> 2;          // staging: 0..63
    const int scol = (tid & 3) << 4;    // 0,16,32,48

    const float* gx0 = x + (size_t)(row0 + srow) * 512 + scol;
    float4* dx = (float4*)&uA[srow * TSTR + scol];
    float4* dw = (float4*)&uA[64 * TSTR + srow * TSTR + scol];

    float4 px[4], pw[4];                 // issue-early / write-late prefetch (regs only)

    float m2[4][8];                      // sims accumulators: rows tlo+16i, regs thi+16j
#pragma unroll
    for (int i = 0; i < 4; ++i)
#pragma unroll
        for (int j = 0; j < 8; ++j) m2[i][j] = 0.f;
    float nacc = 0.f;                    // |xe_row|^2 for tid<64 (exact validated chain)

    for (int dc = 0; dc < 8; ++dc) {
        const float* gw0 = W + (size_t)(dc * 64 + srow) * 512 + scol;

        float m1[4][4];                  // xe accumulators: rows thi+16i, dims tlo+16j
#pragma unroll
        for (int i = 0; i < 4; ++i)
#pragma unroll
            for (int j = 0; j < 4; ++j) m1[i][j] = 0.f;

        for (int kc = 0; kc < 8; ++kc) {
            if (kc == 0) {               // registers only — no LDS hazard with cb overlay
                const float4* gx = (const float4*)(gx0);
                const float4* gw = (const float4*)(gw0);
#pragma unroll
                for (int m = 0; m < 4; ++m) { px[m] = gx[m]; pw[m] = gw[m]; }
            }
            __syncthreads();             // uA x/W region free (prev readers done)
            // write-late: prefetched regs -> LDS (compiler inserts the vmcnt wait)
#pragma unroll
            for (int m = 0; m < 4; ++m) { dx[m] = px[m]; dw[m] = pw[m]; }
            __syncthreads();
            // issue-early: next k-chunk's loads fly under the 16-kk compute
            if (kc < 7) {
                const float4* gx = (const float4*)(gx0 + (kc + 1) * 64);
                const float4* gw = (const float4*)(gw0 + (kc + 1) * 64);
#pragma unroll
                for (int m = 0; m < 4; ++m) { px[m] = gx[m]; pw[m] = gw[m]; }
            }
            // compute (verbatim R4)
            float s1[4][4];
#pragma unroll
            for (int i = 0; i < 4; ++i)
#pragma unroll
                for (int j = 0; j < 4; ++j) s1[i][j] = 0.f;
#pragma unroll
            for (int kk = 0; kk < 16; ++kk) {
                float4 xa[4], wa[4];
#pragma unroll
                for (int i = 0; i < 4; ++i)
                    xa[i] = *(const float4*)&uA[(thi + 16 * i) * TSTR + (kk << 2)];
#pragma unroll
                for (int j = 0; j < 4; ++j)
                    wa[j] = *(const float4*)&uA[64 * TSTR + (tlo + 16 * j) * TSTR + (kk << 2)];
#pragma unroll
                for (int i = 0; i < 4; ++i)
#pragma unroll
                    for (int j = 0; j < 4; ++j) {
                        s1[i][j] = fmaf(xa[i].x, wa[j].x, s1[i][j]);
                        s1[i][j] = fmaf(xa[i].y, wa[j].y, s1[i][j]);
                        s1[i][j] = fmaf(xa[i].z, wa[j].z, s1[i][j]);
                        s1[i][j] = fmaf(xa[i].w, wa[j].w, s1[i][j]);
                    }
            }
#pragma unroll
            for (int i = 0; i < 4; ++i)
#pragma unroll
                for (int j = 0; j < 4; ++j) m1[i][j] += s1[i][j];
        }
        // bias + store xe chunk to LDS (verbatim)
#pragma unroll
        for (int j = 0; j < 4; ++j) {
            float bj = bias[dc * 64 + tlo + 16 * j];
#pragma unroll
            for (int i = 0; i < 4; ++i)
                xeL[(thi + 16 * i) * XESTR + tlo + 16 * j] = m1[i][j] + bj;
        }
        __syncthreads();
        // stage codebook tile [128][64] into uA; norm pass (exact validated order)
        {
            const float4* gr = (const float4*)(cb + (size_t)(tid >> 1) * 512 + dc * 64 + ((tid & 1) << 5));
            float4* dr = (float4*)&uA[(tid >> 1) * TSTR + ((tid & 1) << 5)];
#pragma unroll
            for (int m = 0; m < 8; ++m) dr[m] = gr[m];
        }
        if (tid < 64) {
#pragma unroll
            for (int dd = 0; dd < 16; ++dd) {
                float4 q = *(const float4*)&xeL[tid * XESTR + (dd << 2)];
                nacc = fmaf(q.x, q.x, nacc);
                nacc = fmaf(q.y, q.y, nacc);
                nacc = fmaf(q.z, q.z, nacc);
                nacc = fmaf(q.w, q.w, nacc);
            }
        }
        __syncthreads();
        // phase 2: sims partial over this d-chunk (verbatim)
        float s2[4][8];
#pragma unroll
        for (int i = 0; i < 4; ++i)
#pragma unroll
            for (int j = 0; j < 8; ++j) s2[i][j] = 0.f;
#pragma unroll
        for (int dd = 0; dd < 16; ++dd) {
            float4 xv[4], rv[8];
#pragma unroll
            for (int i = 0; i < 4; ++i)
                xv[i] = *(const float4*)&xeL[(tlo + 16 * i) * XESTR + (dd << 2)];
#pragma unroll
            for (int j = 0; j < 8; ++j)
                rv[j] = *(const float4*)&uA[(thi + 16 * j) * TSTR + (dd << 2)];
#pragma unroll
            for (int i = 0; i < 4; ++i)
#pragma unroll
                for (int j = 0; j < 8; ++j) {
                    s2[i][j] = fmaf(xv[i].x, rv[j].x, s2[i][j]);
                    s2[i][j] = fmaf(xv[i].y, rv[j].y, s2[i][j]);
                    s2[i][j] = fmaf(xv[i].z, rv[j].z, s2[i][j]);
                    s2[i][j] = fmaf(xv[i].w, rv[j].w, s2[i][j]);
                }
        }
#pragma unroll
        for (int i = 0; i < 4; ++i)
#pragma unroll
            for (int j = 0; j < 8; ++j) m2[i][j] += s2[i][j];
    }
    __syncthreads();
    // dump sims numerators to LDS (verbatim addresses/values)
#pragma unroll
    for (int i = 0; i < 4; ++i)
#pragma unroll
        for (int j = 0; j < 8; ++j)
            uA[(tlo + 16 * i) * SSTR + thi + 16 * j] = m2[i][j];
    if (tid < 64) xnL[tid] = sqrtf(nacc);
    __syncthreads();

    // parallel top-3: 4 threads per row, packed keys (exact tie semantics, validated)
    {
        const int row = tid >> 2;
        const int p   = tid & 3;
        const float xn = xnL[row];
        unsigned long long a0 = 0, a1 = 0, a2 = 0;
#pragma unroll
        for (int t = 0; t < 32; ++t) {
            const int c = p + 4 * t;
            float s = uA[row * SSTR + c] / fmaxf(xn * rnL[c], 1e-8f);
            ins3(pack_key(s, c), a0, a1, a2);
        }
#pragma unroll
        for (int mask = 1; mask <= 2; mask <<= 1) {
            unsigned long long b0 = __shfl_xor(a0, mask);
            unsigned long long b1 = __shfl_xor(a1, mask);
            unsigned long long b2 = __shfl_xor(a2, mask);
            ins3(b0, a0, a1, a2); ins3(b1, a0, a1, a2); ins3(b2, a0, a1, a2);
        }
        if (p == 0) {
            const size_t g = (size_t)(row0 + row);
            float* oi = out + idx_off + g * 3;
            float* ov = out + val_off + g * 3;
            oi[0] = (float)key_col(a0); oi[1] = (float)key_col(a1); oi[2] = (float)key_col(a2);
            ov[0] = key_val(a0); ov[1] = key_val(a1); ov[2] = key_val(a2);
            idxL[row * 3 + 0] = (unsigned char)key_col(a0);
            idxL[row * 3 + 1] = (unsigned char)key_col(a1);
            idxL[row * 3 + 2] = (unsigned char)key_col(a2);
        }
    }
    __syncthreads();

    // adapted_centers = cb[idx] + u[tt]*v  (768 tasks over 256 threads, verbatim)
    const float uu0 = u[0], uu1 = u[1], uu2 = u[2];
#pragma unroll
    for (int q = 0; q < 3; ++q) {
        int task = tid + 256 * q;            // 0..767 = 64 rows * 3 tt * 4 seg
        int row = task / 12;
        int rem = task - row * 12;
        int tt  = rem >> 2;
        int seg = rem & 3;
        int idx = idxL[row * 3 + tt];
        float uu = (tt == 0) ? uu0 : ((tt == 1) ? uu1 : uu2);
        const float4* gr4 = (const float4*)(cb + (size_t)idx * 512 + seg * 128);
        const float4* gv4 = (const float4*)(v + seg * 128);
        float4* ob = (float4*)(out + ((size_t)(row0 + row) * 3 + tt) * 512 + seg * 128);
#pragma unroll
        for (int c2 = 0; c2 < 32; ++c2) {
            float4 rv = gr4[c2];
            float4 vv = gv4[c2];
            float4 o;
            o.x = fmaf(uu, vv.x, rv.x);
            o.y = fmaf(uu, vv.y, rv.y);
            o.z = fmaf(uu, vv.z, rv.z);
            o.w = fmaf(uu, vv.w, rv.w);
            ob[c2] = o;
        }
    }
}

extern "C" void kernel_launch(void* const* d_in, const int* in_sizes, int n_in,
                              void* d_out, int out_size, void* d_ws, size_t ws_size,
                              hipStream_t stream) {
    const float* x  = (const float*)d_in[0];
    const float* cb = (const float*)d_in[1];
    const float* W  = (const float*)d_in[2];
    const float* b  = (const float*)d_in[3];
    const float* u  = (const float*)d_in[4];
    const float* v  = (const float*)d_in[5];
    float* rn  = (float*)d_ws;                       // 128 floats scratch
    float* out = (float*)d_out;

    const size_t B = (size_t)in_sizes[0] / 512;      // 131072
    const size_t val_off = (size_t)out_size - 3 * B; // top_k_values
    const size_t idx_off = (size_t)out_size - 6 * B; // top_k_indices

    hipLaunchKernelGGL(rn_kernel, dim3(128), dim3(64), 0, stream, cb, rn);
    hipLaunchKernelGGL(fused_kernel, dim3((unsigned)(B / 64)), dim3(256), 0, stream,
                       x, cb, W, b, u, v, rn, out, idx_off, val_off);
}

// Round 11
// 1771.027 us; speedup vs baseline: 3.4335x; 1.3019x over previous
//
#include <hip/hip_runtime.h>

#define XESTR 68         // xeL row stride (padded, verbatim R4)
#define SSTR 129         // sims dump row stride (verbatim R4)

__device__ __forceinline__ void dma16(const void* g, void* l) {
    __builtin_amdgcn_global_load_lds(
        (const __attribute__((address_space(1))) void*)g,
        (__attribute__((address_space(3))) void*)l, 16, 0, 0);
}

__device__ __forceinline__ unsigned long long pack_key(float s, int col) {
    unsigned u = __float_as_uint(s);
    unsigned m = (u & 0x80000000u) ? ~u : (u | 0x80000000u);
    return ((unsigned long long)m << 32) | (unsigned)(127 - col);
}
__device__ __forceinline__ float key_val(unsigned long long k) {
    unsigned m = (unsigned)(k >> 32);
    unsigned u = (m & 0x80000000u) ? (m ^ 0x80000000u) : ~m;
    return __uint_as_float(u);
}
__device__ __forceinline__ int key_col(unsigned long long k) {
    return 127 - (int)(k & 0xFFFFFFFFu);
}
__device__ __forceinline__ void ins3(unsigned long long x,
        unsigned long long &a0, unsigned long long &a1, unsigned long long &a2) {
    if (x > a0)      { a2 = a1; a1 = a0; a0 = x; }
    else if (x > a1) { a2 = a1; a1 = x; }
    else if (x > a2) { a2 = x; }
}

// codebook row norms, f64 accumulation — verbatim (validated)
__global__ void rn_kernel(const float* __restrict__ cb, float* __restrict__ rn) {
    const int j = blockIdx.x;
    const int t = threadIdx.x;
    double a = 0.0;
#pragma unroll
    for (int m = 0; m < 8; ++m) {
        float f = cb[j * 512 + m * 64 + t];
        a += (double)f * (double)f;
    }
#pragma unroll
    for (int off = 32; off >= 1; off >>= 1)
        a += __shfl_down(a, off);
    if (t == 0) rn[j] = (float)sqrt(a);
}

__global__ __launch_bounds__(256, 3) void fused_kernel(
    const float* __restrict__ x, const float* __restrict__ cb,
    const float* __restrict__ W, const float* __restrict__ bias,
    const float* __restrict__ u, const float* __restrict__ v,
    const float* __restrict__ rn, float* __restrict__ out,
    size_t idx_off, size_t val_off)
{
    // shL: DMA region. x granules [0..1023] (floats 0..4095), W granules (floats 4096..8191);
    // cb overlays floats 0..8191 per dc; sims dump overlays 0..8255 at the end.
    __shared__ __align__(16) float shL[8256];
    __shared__ __align__(16) float xeL[64 * XESTR];  // xe chunk [64][64], padded (verbatim R4)
    __shared__ float rnL[128];
    __shared__ float xnL[64];
    __shared__ unsigned char idxL[64 * 3];

    const int tid = threadIdx.x;
    const int tlo = tid & 15;
    const int thi = tid >> 4;
    const int w   = tid >> 6;          // wave 0..3
    const int l   = tid & 63;          // lane
    const int row0 = blockIdx.x << 6;

    if (tid < 128) rnL[tid] = rn[tid];

    float m2[4][8];                      // sims accumulators: rows tlo+16i, regs thi+16j
#pragma unroll
    for (int i = 0; i < 4; ++i)
#pragma unroll
        for (int j = 0; j < 8; ++j) m2[i][j] = 0.f;
    float nacc = 0.f;                    // |xe_row|^2 for tid<64 (exact validated chain)

    for (int dc = 0; dc < 8; ++dc) {
        float m1[4][4];                  // xe accumulators: rows thi+16i, dims tlo+16j
#pragma unroll
        for (int i = 0; i < 4; ++i)
#pragma unroll
            for (int j = 0; j < 4; ++j) m1[i][j] = 0.f;

        for (int kc = 0; kc < 8; ++kc) {
            __syncthreads();             // prev readers of shL done
            // DMA x tile [64 rows][64 k] and W tile [64 rows][64 k], XOR-swizzled granules.
            // granule P = B + lane; tile pos r=P>>4, gq=(P&15)^(r&7) fetched from global.
#pragma unroll
            for (int m = 0; m < 4; ++m) {
                const int P = (w * 4 + m) * 64 + l;
                const int r = P >> 4;
                const int gq = (P & 15) ^ (r & 7);
                dma16(x + (size_t)(row0 + r) * 512 + kc * 64 + gq * 4,
                      &shL[(w * 4 + m) * 256]);
                dma16(W + (size_t)(dc * 64 + r) * 512 + kc * 64 + gq * 4,
                      &shL[4096 + (w * 4 + m) * 256]);
            }
            __syncthreads();             // implicit vmcnt drain -> tiles ready
            // compute (verbatim R4 math; swizzled read addresses, same values)
            float s1[4][4];
#pragma unroll
            for (int i = 0; i < 4; ++i)
#pragma unroll
                for (int j = 0; j < 4; ++j) s1[i][j] = 0.f;
#pragma unroll
            for (int kk = 0; kk < 16; ++kk) {
                float4 xa[4], wa[4];
#pragma unroll
                for (int i = 0; i < 4; ++i)
                    xa[i] = *(const float4*)&shL[((thi + 16 * i) * 16 + (kk ^ (thi & 7))) * 4];
#pragma unroll
                for (int j = 0; j < 4; ++j)
                    wa[j] = *(const float4*)&shL[4096 + ((tlo + 16 * j) * 16 + (kk ^ (tlo & 7))) * 4];
#pragma unroll
                for (int i = 0; i < 4; ++i)
#pragma unroll
                    for (int j = 0; j < 4; ++j) {
                        s1[i][j] = fmaf(xa[i].x, wa[j].x, s1[i][j]);
                        s1[i][j] = fmaf(xa[i].y, wa[j].y, s1[i][j]);
                        s1[i][j] = fmaf(xa[i].z, wa[j].z, s1[i][j]);
                        s1[i][j] = fmaf(xa[i].w, wa[j].w, s1[i][j]);
                    }
            }
#pragma unroll
            for (int i = 0; i < 4; ++i)
#pragma unroll
                for (int j = 0; j < 4; ++j) m1[i][j] += s1[i][j];
        }
        // bias + store xe chunk to LDS (verbatim)
#pragma unroll
        for (int j = 0; j < 4; ++j) {
            float bj = bias[dc * 64 + tlo + 16 * j];
#pragma unroll
            for (int i = 0; i < 4; ++i)
                xeL[(thi + 16 * i) * XESTR + tlo + 16 * j] = m1[i][j] + bj;
        }
        __syncthreads();                 // kc=7 readers done; xeL visible
        // DMA cb tile [128 rows][64 d] (swizzled) — overlays x/W region; norm overlaps flight
#pragma unroll
        for (int m = 0; m < 8; ++m) {
            const int P = (w * 8 + m) * 64 + l;
            const int r = P >> 4;
            const int gq = (P & 15) ^ (r & 7);
            dma16(cb + (size_t)r * 512 + dc * 64 + gq * 4,
                  &shL[(w * 8 + m) * 256]);
        }
        if (tid < 64) {                  // norm chain (exact validated order)
#pragma unroll
            for (int dd = 0; dd < 16; ++dd) {
                float4 q = *(const float4*)&xeL[tid * XESTR + (dd << 2)];
                nacc = fmaf(q.x, q.x, nacc);
                nacc = fmaf(q.y, q.y, nacc);
                nacc = fmaf(q.z, q.z, nacc);
                nacc = fmaf(q.w, q.w, nacc);
            }
        }
        __syncthreads();                 // drain -> cb ready
        // phase 2: sims partial over this d-chunk (verbatim math)
        float s2[4][8];
#pragma unroll
        for (int i = 0; i < 4; ++i)
#pragma unroll
            for (int j = 0; j < 8; ++j) s2[i][j] = 0.f;
#pragma unroll
        for (int dd = 0; dd < 16; ++dd) {
            float4 xv[4], rv[8];
#pragma unroll
            for (int i = 0; i < 4; ++i)
                xv[i] = *(const float4*)&xeL[(tlo + 16 * i) * XESTR + (dd << 2)];
#pragma unroll
            for (int j = 0; j < 8; ++j)
                rv[j] = *(const float4*)&shL[((thi + 16 * j) * 16 + (dd ^ (thi & 7))) * 4];
#pragma unroll
            for (int i = 0; i < 4; ++i)
#pragma unroll
                for (int j = 0; j < 8; ++j) {
                    s2[i][j] = fmaf(xv[i].x, rv[j].x, s2[i][j]);
                    s2[i][j] = fmaf(xv[i].y, rv[j].y, s2[i][j]);
                    s2[i][j] = fmaf(xv[i].z, rv[j].z, s2[i][j]);
                    s2[i][j] = fmaf(xv[i].w, rv[j].w, s2[i][j]);
                }
        }
#pragma unroll
        for (int i = 0; i < 4; ++i)
#pragma unroll
            for (int j = 0; j < 8; ++j) m2[i][j] += s2[i][j];
    }
    __syncthreads();
    // dump sims numerators (verbatim addresses/values; shL overlay)
#pragma unroll
    for (int i = 0; i < 4; ++i)
#pragma unroll
        for (int j = 0; j < 8; ++j)
            shL[(tlo + 16 * i) * SSTR + thi + 16 * j] = m2[i][j];
    if (tid < 64) xnL[tid] = sqrtf(nacc);
    __syncthreads();

    // parallel top-3: 4 threads per row, packed keys (exact tie semantics, validated)
    {
        const int row = tid >> 2;
        const int p   = tid & 3;
        const float xn = xnL[row];
        unsigned long long a0 = 0, a1 = 0, a2 = 0;
#pragma unroll
        for (int t = 0; t < 32; ++t) {
            const int c = p + 4 * t;
            float s = shL[row * SSTR + c] / fmaxf(xn * rnL[c], 1e-8f);
            ins3(pack_key(s, c), a0, a1, a2);
        }
#pragma unroll
        for (int mask = 1; mask <= 2; mask <<= 1) {
            unsigned long long b0 = __shfl_xor(a0, mask);
            unsigned long long b1 = __shfl_xor(a1, mask);
            unsigned long long b2 = __shfl_xor(a2, mask);
            ins3(b0, a0, a1, a2); ins3(b1, a0, a1, a2); ins3(b2, a0, a1, a2);
        }
        if (p == 0) {
            const size_t g = (size_t)(row0 + row);
            float* oi = out + idx_off + g * 3;
            float* ov = out + val_off + g * 3;
            oi[0] = (float)key_col(a0); oi[1] = (float)key_col(a1); oi[2] = (float)key_col(a2);
            ov[0] = key_val(a0); ov[1] = key_val(a1); ov[2] = key_val(a2);
            idxL[row * 3 + 0] = (unsigned char)key_col(a0);
            idxL[row * 3 + 1] = (unsigned char)key_col(a1);
            idxL[row * 3 + 2] = (unsigned char)key_col(a2);
        }
    }
    __syncthreads();

    // adapted_centers = cb[idx] + u[tt]*v  (768 tasks over 256 threads, verbatim)
    const float uu0 = u[0], uu1 = u[1], uu2 = u[2];
#pragma unroll
    for (int q = 0; q < 3; ++q) {
        int task = tid + 256 * q;            // 0..767 = 64 rows * 3 tt * 4 seg
        int row = task / 12;
        int rem = task - row * 12;
        int tt  = rem >> 2;
        int seg = rem & 3;
        int idx = idxL[row * 3 + tt];
        float uu = (tt == 0) ? uu0 : ((tt == 1) ? uu1 : uu2);
        const float4* gr4 = (const float4*)(cb + (size_t)idx * 512 + seg * 128);
        const float4* gv4 = (const float4*)(v + seg * 128);
        float4* ob = (float4*)(out + ((size_t)(row0 + row) * 3 + tt) * 512 + seg * 128);
#pragma unroll
        for (int c2 = 0; c2 < 32; ++c2) {
            float4 rv = gr4[c2];
            float4 vv = gv4[c2];
            float4 o;
            o.x = fmaf(uu, vv.x, rv.x);
            o.y = fmaf(uu, vv.y, rv.y);
            o.z = fmaf(uu, vv.z, rv.z);
            o.w = fmaf(uu, vv.w, rv.w);
            ob[c2] = o;
        }
    }
}

extern "C" void kernel_launch(void* const* d_in, const int* in_sizes, int n_in,
                              void* d_out, int out_size, void* d_ws, size_t ws_size,
                              hipStream_t stream) {
    const float* x  = (const float*)d_in[0];
    const float* cb = (const float*)d_in[1];
    const float* W  = (const float*)d_in[2];
    const float* b  = (const float*)d_in[3];
    const float* u  = (const float*)d_in[4];
    const float* v  = (const float*)d_in[5];
    float* rn  = (float*)d_ws;                       // 128 floats scratch
    float* out = (float*)d_out;

    const size_t B = (size_t)in_sizes[0] / 512;      // 131072
    const size_t val_off = (size_t)out_size - 3 * B; // top_k_values
    const size_t idx_off = (size_t)out_size - 6 * B; // top_k_indices

    hipLaunchKernelGGL(rn_kernel, dim3(128), dim3(64), 0, stream, cb, rn);
    hipLaunchKernelGGL(fused_kernel, dim3((unsigned)(B / 64)), dim3(256), 0, stream,
                       x, cb, W, b, u, v, rn, out, idx_off, val_off);
}